// Round 8
// baseline (623.892 us; speedup 1.0000x reference)
//
#include <hip/hip_runtime.h>

// ---------------------------------------------------------------------------
// QuietSTaRAttention on MI355X (gfx950). External I/O: FLOAT32.
// B=2, S=2048, R=128, E=2048, H=16, D=128.
//
// Round 8: (a) attn __launch_bounds__(256,4) — force <=128 VGPR => 4 blocks/CU
// (was 140 VGPR / 3 blocks); (b) revert split-KV (r6 proved it occupancy-
// neutral): z=1, attn normalizes in-kernel and writes OB [token][E] directly,
// combine_k deleted, 64MB of partial traffic gone. S^T/P^T shfl formulation
// kept (r7-verified). gemm/prep kernels byte-identical to r6/r7.
// ---------------------------------------------------------------------------

typedef __bf16 bf16;
typedef __bf16 bf16x4 __attribute__((ext_vector_type(4)));
typedef __bf16 bf16x8 __attribute__((ext_vector_type(8)));
typedef float  f32x4  __attribute__((ext_vector_type(4)));
typedef float  f32x16 __attribute__((ext_vector_type(16)));
typedef int    i32x4  __attribute__((ext_vector_type(4)));
typedef char   char8  __attribute__((ext_vector_type(8)));

#define B_   2
#define S_   2048
#define R_   128
#define E_   2048
#define H_   16
#define D_   128
#define NKV  2176   // S_+R_
#define NTOK 4096   // B_*S_
#define KDIM 2048

typedef const __attribute__((address_space(1))) void* gas_ptr;
typedef __attribute__((address_space(3))) void*       las_ptr;

__device__ __forceinline__ void load_lds16(const void* g, void* l) {
  __builtin_amdgcn_global_load_lds((gas_ptr)g, (las_ptr)l, 16, 0, 0);
}

// ---------------- 1. |w| sum (fp64 accumulate) -----------------------------
__global__ __launch_bounds__(256) void abs_sum_k(
    const float* __restrict__ w0, const float* __restrict__ w1,
    const float* __restrict__ w2, double* wsD) {
  int z = blockIdx.y;
  const float* w = z == 0 ? w0 : (z == 1 ? w1 : w2);
  int tid = threadIdx.x;
  size_t base = ((size_t)blockIdx.x * 256 + tid) * 8;
  f32x4 a = *(const f32x4*)(w + base);
  f32x4 b = *(const f32x4*)(w + base + 4);
  float s = 0.f;
#pragma unroll
  for (int j = 0; j < 4; j++) s += fabsf(a[j]) + fabsf(b[j]);
  double d = (double)s;
#pragma unroll
  for (int m = 1; m < 64; m <<= 1) d += __shfl_xor(d, m);
  __shared__ double red[4];
  if ((tid & 63) == 0) red[tid >> 6] = d;
  __syncthreads();
  if (tid == 0) atomicAdd(&wsD[z], red[0] + red[1] + red[2] + red[3]);
}

// ---------------- 2. fused prep: ternary->i8 (y<3), f32->bf16 casts --------
__global__ __launch_bounds__(256) void prep_k(
    const float* __restrict__ qw, const float* __restrict__ kw,
    const float* __restrict__ vw, const float* __restrict__ ow,
    const float* __restrict__ rt, const double* __restrict__ wsD, float* wsF,
    char* __restrict__ TQ8, char* __restrict__ TK8, char* __restrict__ TV8,
    bf16* __restrict__ KWb, bf16* __restrict__ VWb, bf16* __restrict__ OWb,
    bf16* __restrict__ RTb) {
  int y = blockIdx.y;
  if (y < 3) {
    const float* w = y == 0 ? qw : (y == 1 ? kw : vw);
    char* t        = y == 0 ? TQ8 : (y == 1 ? TK8 : TV8);
    float scale = (float)fmax(wsD[y] * (1.0 / 4194304.0), 1e-5);
    if (blockIdx.x == 0 && threadIdx.x == 0) wsF[y] = scale;
    size_t base = ((size_t)blockIdx.x * 256 + threadIdx.x) * 8;
    f32x4 a = *(const f32x4*)(w + base);
    f32x4 b = *(const f32x4*)(w + base + 4);
    float rs = 1.0f / scale;
    char8 o;
#pragma unroll
    for (int j = 0; j < 8; j++) {
      float v = j < 4 ? a[j] : b[j - 4];
      float q = rintf(v * rs);
      q = fminf(fmaxf(q, -1.f), 1.f);
      o[j] = (char)(int)q;
    }
    *(char8*)(t + base) = o;
  } else {
    if (y == 6 && blockIdx.x >= 256) return;
    const float* src = y == 3 ? kw : (y == 4 ? vw : (y == 5 ? ow : rt));
    bf16* dst        = y == 3 ? KWb : (y == 4 ? VWb : (y == 5 ? OWb : RTb));
    size_t i = ((size_t)blockIdx.x * 256 + threadIdx.x) * 8;
    f32x4 a = *(const f32x4*)(src + i);
    f32x4 b = *(const f32x4*)(src + i + 4);
    bf16x8 o;
#pragma unroll
    for (int j = 0; j < 4; j++) { o[j] = (bf16)a[j]; o[j + 4] = (bf16)b[j]; }
    *(bf16x8*)(dst + i) = o;
  }
}

// ---------------- 3. per-token activation quantization -> int8 -------------
__global__ __launch_bounds__(256) void actq_k(
    const float* __restrict__ x, char* __restrict__ xq,
    float* __restrict__ aScale) {
  int row = blockIdx.x, tid = threadIdx.x;
  const float* xr = x + (size_t)row * E_;
  f32x4 a = *(const f32x4*)(xr + tid * 8);
  f32x4 b = *(const f32x4*)(xr + tid * 8 + 4);
  float am = 0.f;
#pragma unroll
  for (int j = 0; j < 4; j++) am = fmaxf(am, fmaxf(fabsf(a[j]), fabsf(b[j])));
#pragma unroll
  for (int m = 1; m < 64; m <<= 1) am = fmaxf(am, __shfl_xor(am, m));
  __shared__ float red[4];
  if ((tid & 63) == 0) red[tid >> 6] = am;
  __syncthreads();
  float mx = fmaxf(fmaxf(red[0], red[1]), fmaxf(red[2], red[3]));
  float maxC = fmaxf(mx, 1e-5f);
  float s = 127.0f / maxC;
  char8 o;
#pragma unroll
  for (int j = 0; j < 8; j++) {
    float v = j < 4 ? a[j] : b[j - 4];
    float q = rintf(v * s);
    q = fminf(fmaxf(q, -128.f), 127.f);
    o[j] = (char)(int)q;
  }
  *(char8*)(xq + (size_t)row * E_ + tid * 8) = o;
  if (tid == 0) aScale[row] = maxC / 127.0f;
}

// ---------------- bf16 GEMM core: 128x128 tile, BK=32 ----------------------
__device__ __forceinline__ void gemm_core(const bf16* Arow, const bf16* Brow,
                                          bf16* As, bf16* Bs, int tid,
                                          f32x4 acc[4][4]) {
  int wave = tid >> 6, lane = tid & 63, quad = lane >> 4, l16 = lane & 15;
  int wm = wave >> 1, wn = wave & 1;
  const char* aT = (const char*)Arow;
  const char* bT = (const char*)Brow;
  int c1 = tid + 256;
  size_t aO0 = (size_t)(tid >> 2) * (KDIM * 2) + (size_t)(tid & 3) * 16;
  size_t aO1 = (size_t)(c1 >> 2) * (KDIM * 2) + (size_t)(c1 & 3) * 16;
  char* AsB = (char*)As;
  char* BsB = (char*)Bs;
  int wofs = wave * 1024;
  for (int k0 = 0; k0 < KDIM; k0 += 32) {
    __syncthreads();
    load_lds16(aT + aO0, AsB + wofs);
    load_lds16(aT + aO1, AsB + 4096 + wofs);
    load_lds16(bT + aO0, BsB + wofs);
    load_lds16(bT + aO1, BsB + 4096 + wofs);
    aT += 64;
    bT += 64;
    __syncthreads();
    bf16x8 af[4], bfr[4];
#pragma unroll
    for (int mt = 0; mt < 4; mt++)
      af[mt] = *(const bf16x8*)(As + (wm * 64 + mt * 16 + l16) * 32 + quad * 8);
#pragma unroll
    for (int nt = 0; nt < 4; nt++)
      bfr[nt] = *(const bf16x8*)(Bs + (wn * 64 + nt * 16 + l16) * 32 + quad * 8);
#pragma unroll
    for (int mt = 0; mt < 4; mt++)
#pragma unroll
      for (int nt = 0; nt < 4; nt++)
        acc[mt][nt] = __builtin_amdgcn_mfma_f32_16x16x32_bf16(
            af[mt], bfr[nt], acc[mt][nt], 0, 0, 0);
  }
}

// ---------------- i8 GEMM core: 128x128 tile, BK=64 ------------------------
__device__ __forceinline__ void gemm_core_i8(const char* Arow, const char* Brow,
                                             char* As, char* Bs, int tid,
                                             i32x4 acc[4][4]) {
  int wave = tid >> 6, lane = tid & 63, quad = lane >> 4, l16 = lane & 15;
  int wm = wave >> 1, wn = wave & 1;
  int s0 = tid, s1 = tid + 256;
  int r0 = s0 >> 2, r1 = s1 >> 2;
  size_t aO0 = (size_t)r0 * KDIM + (size_t)((s0 & 3) ^ (r0 & 3)) * 16;
  size_t aO1 = (size_t)r1 * KDIM + (size_t)((s1 & 3) ^ (r1 & 3)) * 16;
  const char* aT = Arow;
  const char* bT = Brow;
  int wofs = wave * 1024;
  int cs = (quad ^ (l16 & 3)) * 16;
  for (int k0 = 0; k0 < KDIM; k0 += 64) {
    __syncthreads();
    load_lds16(aT + aO0, As + wofs);
    load_lds16(aT + aO1, As + 4096 + wofs);
    load_lds16(bT + aO0, Bs + wofs);
    load_lds16(bT + aO1, Bs + 4096 + wofs);
    aT += 64;
    bT += 64;
    __syncthreads();
    i32x4 af[4], bfr[4];
#pragma unroll
    for (int mt = 0; mt < 4; mt++)
      af[mt] = *(const i32x4*)(As + (wm * 64 + mt * 16 + l16) * 64 + cs);
#pragma unroll
    for (int nt = 0; nt < 4; nt++)
      bfr[nt] = *(const i32x4*)(Bs + (wn * 64 + nt * 16 + l16) * 64 + cs);
#pragma unroll
    for (int mt = 0; mt < 4; mt++)
#pragma unroll
      for (int nt = 0; nt < 4; nt++)
        acc[mt][nt] = __builtin_amdgcn_mfma_i32_16x16x64_i8(
            af[mt], bfr[nt], acc[mt][nt], 0, 0, 0);
  }
}

// ---------------- merged projection GEMM (unchanged from r6) ---------------
__global__ __launch_bounds__(256) void gemm_proj(
    const char* __restrict__ XQ8, const char* __restrict__ TQ8,
    const char* __restrict__ TK8, const char* __restrict__ TV8,
    const bf16* __restrict__ RTb, const bf16* __restrict__ KWb,
    const bf16* __restrict__ VWb, const float* __restrict__ asc,
    const float* __restrict__ wsF, bf16* __restrict__ QB,
    bf16* __restrict__ KB, bf16* __restrict__ VT) {
  __shared__ char As[8192];
  __shared__ char Bs[8192];
  int tid = threadIdx.x;
  int lane = tid & 63, quad = lane >> 4, l16 = lane & 15;
  int wm = (tid >> 6) >> 1, wn = (tid >> 6) & 1;

  if (blockIdx.y < 32) {  // ---- QK-role ----
    int m0 = blockIdx.x * 128, n0 = blockIdx.y * 128;
    bool isQ = n0 < 2048;
    bool isRsn = m0 >= NTOK;
    if (isQ && isRsn) return;
    if (!isRsn) {
      const char* Bm = isQ ? (TQ8 + (size_t)n0 * KDIM)
                           : (TK8 + (size_t)(n0 - 2048) * KDIM);
      float sW = isQ ? wsF[0] : wsF[1];
      i32x4 acc[4][4];
      const i32x4 iz = {0, 0, 0, 0};
#pragma unroll
      for (int i = 0; i < 4; i++)
#pragma unroll
        for (int j = 0; j < 4; j++) acc[i][j] = iz;
      gemm_core_i8(XQ8 + (size_t)m0 * KDIM, Bm, As, Bs, tid, acc);
#pragma unroll
      for (int mt = 0; mt < 4; mt++) {
        int mB = m0 + wm * 64 + mt * 16 + quad * 4;
#pragma unroll
        for (int nt = 0; nt < 4; nt++) {
          int n = n0 + wn * 64 + nt * 16 + l16;
          int nn = n & 2047, h = nn >> 7, d = nn & 127;
#pragma unroll
          for (int r = 0; r < 4; r++) {
            int m = mB + r;
            float v = (float)acc[mt][nt][r] * asc[m] * sW;
            int tb = m >> 11, ts = m & 2047;
            if (isQ)
              QB[((size_t)((tb * 16 + h) * S_ + ts)) * 128 + d] = (bf16)v;
            else
              KB[((size_t)((tb * 16 + h) * NKV + ts)) * 128 + d] = (bf16)v;
          }
        }
      }
    } else {
      f32x4 acc[4][4];
      const f32x4 fz = {0.f, 0.f, 0.f, 0.f};
#pragma unroll
      for (int i = 0; i < 4; i++)
#pragma unroll
        for (int j = 0; j < 4; j++) acc[i][j] = fz;
      gemm_core(RTb + (size_t)(m0 - NTOK) * KDIM,
                KWb + (size_t)(n0 - 2048) * KDIM, (bf16*)As, (bf16*)Bs, tid,
                acc);
#pragma unroll
      for (int mt = 0; mt < 4; mt++) {
        int mB = m0 + wm * 64 + mt * 16 + quad * 4;
#pragma unroll
        for (int nt = 0; nt < 4; nt++) {
          int n = n0 + wn * 64 + nt * 16 + l16;
          int nn = n & 2047, h = nn >> 7, d = nn & 127;
#pragma unroll
          for (int r = 0; r < 4; r++) {
            int j = mB + r - NTOK;
            int tb = j >> 7, ts = 2048 + (j & 127);
            KB[((size_t)((tb * 16 + h) * NKV + ts)) * 128 + d] =
                (bf16)acc[mt][nt][r];
          }
        }
      }
    }
  } else {  // ---- V^T-role ----
    int m0 = (blockIdx.y - 32) * 128, n0 = blockIdx.x * 128;
    bool isRsn = n0 >= NTOK;
    if (!isRsn) {
      i32x4 acc[4][4];
      const i32x4 iz = {0, 0, 0, 0};
#pragma unroll
      for (int i = 0; i < 4; i++)
#pragma unroll
        for (int j = 0; j < 4; j++) acc[i][j] = iz;
      gemm_core_i8(TV8 + (size_t)m0 * KDIM, XQ8 + (size_t)n0 * KDIM, As, Bs,
                   tid, acc);
#pragma unroll
      for (int mt = 0; mt < 4; mt++) {
        int mB = m0 + wm * 64 + mt * 16 + quad * 4;
#pragma unroll
        for (int nt = 0; nt < 4; nt++) {
          int n = n0 + wn * 64 + nt * 16 + l16;
          float sb = asc[n] * wsF[2];
          int tb = n >> 11, ts = n & 2047;
#pragma unroll
          for (int r = 0; r < 4; r++) {
            int m = mB + r, h = m >> 7, d = m & 127;
            VT[((size_t)((tb * 16 + h) * 128 + d)) * NKV + ts] =
                (bf16)((float)acc[mt][nt][r] * sb);
          }
        }
      }
    } else {
      f32x4 acc[4][4];
      const f32x4 fz = {0.f, 0.f, 0.f, 0.f};
#pragma unroll
      for (int i = 0; i < 4; i++)
#pragma unroll
        for (int j = 0; j < 4; j++) acc[i][j] = fz;
      gemm_core(VWb + (size_t)m0 * KDIM, RTb + (size_t)(n0 - NTOK) * KDIM,
                (bf16*)As, (bf16*)Bs, tid, acc);
#pragma unroll
      for (int mt = 0; mt < 4; mt++) {
        int mB = m0 + wm * 64 + mt * 16 + quad * 4;
#pragma unroll
        for (int nt = 0; nt < 4; nt++) {
          int n = n0 + wn * 64 + nt * 16 + l16;
          int j = n - NTOK, tb = j >> 7, ts = 2048 + (j & 127);
#pragma unroll
          for (int r = 0; r < 4; r++) {
            int m = mB + r, h = m >> 7, d = m & 127;
            VT[((size_t)((tb * 16 + h) * 128 + d)) * NKV + ts] =
                (bf16)acc[mt][nt][r];
          }
        }
      }
    }
  }
}

// ---------------- output projection: out = OB @ OWb^T + bias (f32) ---------
__global__ __launch_bounds__(256) void gemm_out(
    const bf16* __restrict__ A, const bf16* __restrict__ Bm,
    const float* __restrict__ bias, float* __restrict__ out) {
  __shared__ bf16 As[128 * 32];
  __shared__ bf16 Bs[128 * 32];
  int m0 = blockIdx.x * 128, n0 = blockIdx.y * 128;
  int tid = threadIdx.x;
  int lane = tid & 63, quad = lane >> 4, l16 = lane & 15;
  int wm = (tid >> 6) >> 1, wn = (tid >> 6) & 1;

  f32x4 acc[4][4];
  const f32x4 fz = {0.f, 0.f, 0.f, 0.f};
#pragma unroll
  for (int i = 0; i < 4; i++)
#pragma unroll
    for (int j = 0; j < 4; j++) acc[i][j] = fz;
  gemm_core(A + (size_t)m0 * KDIM, Bm + (size_t)n0 * KDIM, As, Bs, tid, acc);

#pragma unroll
  for (int mt = 0; mt < 4; mt++) {
    int mB = m0 + wm * 64 + mt * 16 + quad * 4;
#pragma unroll
    for (int nt = 0; nt < 4; nt++) {
      int n = n0 + wn * 64 + nt * 16 + l16;
      float bv = bias[n];
#pragma unroll
      for (int r = 0; r < 4; r++)
        out[(size_t)(mB + r) * E_ + n] = acc[mt][nt][r] + bv;
    }
  }
}

// ---------------- flash attention: S^T via 32x32x16, full KV, direct OB ----
// grid (16, 32); 4 waves, wave w owns q-rows [q0+32w, q0+32w+32).
// __launch_bounds__(256,4): cap 128 VGPR -> 4 blocks/CU (was 140/3).
// Normalizes in-kernel (fixed-shift softmax row-sum over all 34 tiles) and
// writes OB in [token][E] layout directly.
__global__ __launch_bounds__(256, 4) void attn_k(
    const bf16* __restrict__ q, const bf16* __restrict__ k,
    const bf16* __restrict__ vt, bf16* __restrict__ OB) {
  __shared__ bf16 Ks[64 * 128];   // [key][d], 256B rows, chunk c at c^(row&15)
  __shared__ bf16 Vs[128 * 64];   // [d][key], 128B rows, chunk c at c^(row&7)
  const float SC = 0.08838834764831845f;  // 1/sqrt(128)
  const float SHIFT = 12.0f;
  int tid = threadIdx.x;
  int wave = tid >> 6, lane = tid & 63, hh = lane >> 5, l31 = lane & 31;
  int bh = blockIdx.y, q0 = blockIdx.x * 128;

  const bf16* qb = q + ((size_t)bh * S_ + q0 + wave * 32 + l31) * D_;
  const char* kb = (const char*)(k + (size_t)bh * NKV * D_);
  const char* vb = (const char*)(vt + (size_t)bh * D_ * NKV);

  bf16x8 qf[8];
#pragma unroll
  for (int ds = 0; ds < 8; ds++)
    qf[ds] = *(const bf16x8*)(qb + ds * 16 + hh * 8);

  f32x16 oa[4];
#pragma unroll
  for (int i = 0; i < 4; i++)
#pragma unroll
    for (int r = 0; r < 16; r++) oa[i][r] = 0.f;
  float lsum = 0.f;

  char* KsB = (char*)Ks;
  char* VsB = (char*)Vs;

  int kRow[4], kC[4], vRow[4], vC[4];
#pragma unroll
  for (int i = 0; i < 4; i++) {
    int slot = i * 256 + tid;
    kRow[i] = slot >> 4;
    kC[i] = (slot & 15) ^ (kRow[i] & 15);
    vRow[i] = slot >> 3;
    vC[i] = (slot & 7) ^ (vRow[i] & 7);
  }
  int wofs = wave * 1024;

  for (int kv = 0; kv < NKV; kv += 64) {
    __syncthreads();
#pragma unroll
    for (int i = 0; i < 4; i++)
      load_lds16(kb + (size_t)(kv + kRow[i]) * 256 + kC[i] * 16,
                 KsB + i * 4096 + wofs);
#pragma unroll
    for (int i = 0; i < 4; i++)
      load_lds16(vb + (size_t)vRow[i] * (NKV * 2) + (size_t)kv * 2 + vC[i] * 16,
                 VsB + i * 4096 + wofs);
    __syncthreads();

#pragma unroll
    for (int kb2 = 0; kb2 < 2; kb2++) {
      f32x16 st;
#pragma unroll
      for (int r = 0; r < 16; r++) st[r] = 0.f;
      int krow = kb2 * 32 + l31;
#pragma unroll
      for (int ds = 0; ds < 8; ds++) {
        int c0 = ds * 2 + hh;
        bf16x8 kf = *(const bf16x8*)(KsB + krow * 256 +
                                     ((c0 ^ (krow & 15)) * 16));
        st = __builtin_amdgcn_mfma_f32_32x32x16_bf16(kf, qf[ds], st, 0, 0, 0);
      }
      union {
        bf16 b[16];
        int w[8];
      } pu;
#pragma unroll
      for (int r = 0; r < 16; r++) {
        float e = __expf(st[r] * SC - SHIFT);
        lsum += e;
        pu.b[r] = (bf16)e;
      }
#pragma unroll
      for (int w16 = 0; w16 < 2; w16++) {
        int w0 = pu.w[4 * w16 + 0], w1 = pu.w[4 * w16 + 1];
        int w2 = pu.w[4 * w16 + 2], w3 = pu.w[4 * w16 + 3];
        int s0 = __shfl_xor(w0, 32), s1 = __shfl_xor(w1, 32);
        int s2 = __shfl_xor(w2, 32), s3 = __shfl_xor(w3, 32);
        union {
          int w[4];
          bf16x8 v;
        } fu;
        fu.w[0] = hh ? s2 : w0;
        fu.w[1] = hh ? s3 : w1;
        fu.w[2] = hh ? w2 : s0;
        fu.w[3] = hh ? w3 : s1;
#pragma unroll
        for (int db = 0; db < 4; db++) {
          int vrow = db * 32 + l31;
          int c0 = kb2 * 4 + w16 * 2 + hh;
          bf16x8 vf = *(const bf16x8*)(VsB + vrow * 128 +
                                       ((c0 ^ (vrow & 7)) * 16));
          oa[db] = __builtin_amdgcn_mfma_f32_32x32x16_bf16(vf, fu.v, oa[db],
                                                           0, 0, 0);
        }
      }
    }
  }

  // epilogue: full-row normalize, write OB [token][E] directly
  float lred = lsum + __shfl_xor(lsum, 32);
  float rl = 1.0f / lred;
  int b = bh >> 4, h = bh & 15;
  int s = q0 + wave * 32 + l31;
  size_t obase = ((size_t)(b * S_ + s)) * E_ + h * 128;
#pragma unroll
  for (int db = 0; db < 4; db++)
#pragma unroll
    for (int g = 0; g < 4; g++) {
      int d = 8 * g + 4 * hh + 32 * db;
      bf16x4 o4;
#pragma unroll
      for (int r = 0; r < 4; r++) o4[r] = (bf16)(oa[db][4 * g + r] * rl);
      *(bf16x4*)(OB + obase + d) = o4;
    }
}

// ---------------- workspace layout (99.6 MB, unchanged) --------------------
static constexpr size_t O_ASC = 256;
static constexpr size_t O_XQ8 = 32768;
static constexpr size_t O_RTB = O_XQ8 + 8388608;
static constexpr size_t O_TQ8 = O_RTB + 1048576;
static constexpr size_t O_TK8 = O_TQ8 + 4194304;
static constexpr size_t O_TV8 = O_TK8 + 4194304;
static constexpr size_t O_KWB = O_TV8 + 4194304;
static constexpr size_t O_VWB = O_KWB + 8388608;
static constexpr size_t O_OWB = O_VWB + 8388608;
static constexpr size_t O_QB  = O_OWB + 8388608;
static constexpr size_t O_KB  = O_QB + 16777216;
static constexpr size_t O_VT  = O_KB + 17825792;
static constexpr size_t WS_NEED = O_VT + 17825792;      // 99,647,488
// OB (16MB) overlays XQ8+RTB+TQ8+TK8 (17MB, all dead after gemm_proj; attn
// reads only QB/KB/VT and writes OB here):
static constexpr size_t O_OB = O_XQ8;

extern "C" void kernel_launch(void* const* d_in, const int* in_sizes, int n_in,
                              void* d_out, int out_size, void* d_ws,
                              size_t ws_size, hipStream_t stream) {
  const float* x  = (const float*)d_in[0];
  const float* rt = (const float*)d_in[1];
  const float* qw = (const float*)d_in[2];
  const float* kw = (const float*)d_in[3];
  const float* vw = (const float*)d_in[4];
  const float* ow = (const float*)d_in[5];
  const float* ob = (const float*)d_in[6];
  char* ws = (char*)d_ws;
  if (ws_size < WS_NEED) return;

  double* wsD = (double*)ws;
  float* wsF  = (float*)(ws + 64);
  float* asc  = (float*)(ws + O_ASC);
  char* XQ8 = ws + O_XQ8;
  bf16* RTb = (bf16*)(ws + O_RTB);
  char* TQ8 = ws + O_TQ8;
  char* TK8 = ws + O_TK8;
  char* TV8 = ws + O_TV8;
  bf16* KWb = (bf16*)(ws + O_KWB);
  bf16* VWb = (bf16*)(ws + O_VWB);
  bf16* OWb = (bf16*)(ws + O_OWB);
  bf16* QB  = (bf16*)(ws + O_QB);
  bf16* KB  = (bf16*)(ws + O_KB);
  bf16* VT  = (bf16*)(ws + O_VT);
  bf16* OB  = (bf16*)(ws + O_OB);
  float* out = (float*)d_out;

  hipMemsetAsync(ws, 0, 64, stream);
  abs_sum_k<<<dim3(2048, 3), 256, 0, stream>>>(qw, kw, vw, wsD);
  prep_k<<<dim3(2048, 7), 256, 0, stream>>>(qw, kw, vw, ow, rt, wsD, wsF,
                                            TQ8, TK8, TV8, KWb, VWb, OWb, RTb);
  actq_k<<<4096, 256, 0, stream>>>(x, XQ8, asc);

  gemm_proj<<<dim3(34, 48), 256, 0, stream>>>(XQ8, TQ8, TK8, TV8, RTb, KWb,
                                              VWb, asc, wsF, QB, KB, VT);

  attn_k<<<dim3(16, 32), 256, 0, stream>>>(QB, KB, VT, OB);

  gemm_out<<<dim3(32, 16), 256, 0, stream>>>(OB, OWb, ob, out);
}